// Round 7
// baseline (618.733 us; speedup 1.0000x reference)
//
#include <hip/hip_runtime.h>
#include <hip/hip_bf16.h>
#include <cstdint>
#include <cstddef>

// Problem constants (B=2, N=1024, C=512, H=8, hd=64, clusters=8)
#define NB   2
#define NN   1024
#define NC   512
#define NH   8
#define NHD  64
#define NK   8

typedef __attribute__((ext_vector_type(8))) short short8v;   // 8 bf16 (4 VGPRs)
typedef __attribute__((ext_vector_type(4))) short short4v;
typedef __attribute__((ext_vector_type(4))) float f32x4;

__device__ __forceinline__ short f2bf(float f) {
    union { float f; unsigned u; } v; v.f = f;
    unsigned r = v.u + 0x7FFFu + ((v.u >> 16) & 1u);   // RNE
    return (short)(r >> 16);
}
__device__ __forceinline__ float bf2f(short s) {
    union { unsigned u; float f; } v;
    v.u = ((unsigned)(unsigned short)s) << 16;
    return v.f;
}
__device__ __forceinline__ short8v cvt8(const float* p) {
    float4 a = *(const float4*)p;
    float4 b = *(const float4*)(p + 4);
    short8v r;
    r[0] = f2bf(a.x); r[1] = f2bf(a.y); r[2] = f2bf(a.z); r[3] = f2bf(a.w);
    r[4] = f2bf(b.x); r[5] = f2bf(b.y); r[6] = f2bf(b.z); r[7] = f2bf(b.w);
    return r;
}

// ---------------------------------------------------------------- QKV GEMM (inline f32->bf16 cast)
// q/k: (2048,512) bf16.  v stored transposed per head: vT[b,h,d,i] bf16.
__global__ __launch_bounds__(256) void qkv_kernel(
    const float* __restrict__ x, const float* __restrict__ wq,
    const float* __restrict__ wk, const float* __restrict__ wv,
    short* __restrict__ qb, short* __restrict__ kb, short* __restrict__ vT) {
    __shared__ short As[64][40];
    __shared__ short Bs[64][40];
    const int tid = threadIdx.x;
    const int z = blockIdx.z;
    const float* Bsrc = (z == 0) ? wq : ((z == 1) ? wk : wv);
    const int m0 = blockIdx.y * 64, n0 = blockIdx.x * 64;
    const int lane = tid & 63, wave = tid >> 6;
    const int wm = wave >> 1, wn = wave & 1, quad = lane >> 4, lr = lane & 15;
    const int row = tid >> 2, c0 = (tid & 3) * 8;
    f32x4 acc[2][2] = {};
    for (int kt = 0; kt < 512; kt += 32) {
        *(short8v*)&As[row][c0] = cvt8(x + (m0 + row) * 512 + kt + c0);
        *(short8v*)&Bs[row][c0] = cvt8(Bsrc + (n0 + row) * 512 + kt + c0);
        __syncthreads();
        short8v a0 = *(short8v*)&As[wm * 32 + lr][quad * 8];
        short8v a1 = *(short8v*)&As[wm * 32 + 16 + lr][quad * 8];
        short8v b0 = *(short8v*)&Bs[wn * 32 + lr][quad * 8];
        short8v b1 = *(short8v*)&Bs[wn * 32 + 16 + lr][quad * 8];
        acc[0][0] = __builtin_amdgcn_mfma_f32_16x16x32_bf16(a0, b0, acc[0][0], 0, 0, 0);
        acc[0][1] = __builtin_amdgcn_mfma_f32_16x16x32_bf16(a0, b1, acc[0][1], 0, 0, 0);
        acc[1][0] = __builtin_amdgcn_mfma_f32_16x16x32_bf16(a1, b0, acc[1][0], 0, 0, 0);
        acc[1][1] = __builtin_amdgcn_mfma_f32_16x16x32_bf16(a1, b1, acc[1][1], 0, 0, 0);
        __syncthreads();
    }
    for (int sm = 0; sm < 2; sm++)
        for (int sn = 0; sn < 2; sn++)
            for (int r = 0; r < 4; r++) {
                int m = m0 + wm * 32 + sm * 16 + quad * 4 + r;
                int n = n0 + wn * 32 + sn * 16 + lr;
                short v = f2bf(acc[sm][sn][r]);
                if (z == 0) qb[m * 512 + n] = v;
                else if (z == 1) kb[m * 512 + n] = v;
                else {
                    int bb = m >> 10, i = m & 1023, h = n >> 6, d = n & 63;
                    vT[(size_t)(((bb * 8 + h) * 64 + d) << 10) + i] = v;
                }
            }
}

// ---------------------------------------------------------------- fused attention (16-row strips)
// Grid (64,16) = 1024 blocks. Per block: j-loop computes s=scale*q k^T, masks,
// exp -> Es, masked-s (bf16) -> Sm strip in LDS, o += e@v, colsum accumulates.
// Then a barrier-free WRITE PHASE streams all 8 cluster slices as full
// contiguous 4 KB rows (plain f32x4 stores - the fill kernel's proven shape).
__global__ __launch_bounds__(256) void attn_fused_kernel(
    const short* __restrict__ qb, const short* __restrict__ kb,
    const short* __restrict__ vT, const int* __restrict__ idx,
    float* __restrict__ attn, short* __restrict__ oh) {
    __shared__ short Sm[16][1032];               // masked s strip (bf16), +8 pad
    __shared__ short Qs[16][72], Ks[64][72], Vs[64][72], Es[16][72];
    __shared__ float Ss[16][68];
    __shared__ float rowpart[16][17];
    __shared__ float cpart[64][5];
    __shared__ float invL[16], csL[64];
    __shared__ int idxi[16], idxj[64];
    const int tid = threadIdx.x;
    const int z = blockIdx.y, b = z >> 3, h = z & 7;
    const int i0 = blockIdx.x * 16;
    const int lane = tid & 63, wave = tid >> 6;     // wave = 16-col chunk (j for s, d for o)
    const int quad = lane >> 4, lr = lane & 15;
    const int r0 = tid >> 3, cc8 = (tid & 7) * 8;   // staging: rows 0..31
    const int rL = tid >> 4, cI = tid & 15, cL = cI * 4;   // epilogue mapping
    {
        int rq = tid >> 4, cq = (tid & 15) * 4;
        *(short4v*)&Qs[rq][cq] = *(const short4v*)(qb + (b * 1024 + i0 + rq) * 512 + h * 64 + cq);
    }
    if (tid < 16) idxi[tid] = idx[b * 1024 + i0 + tid];
    f32x4 acc_o = {};
    float rsum = 0.f;    // row rL
    float csum = 0.f;    // colsum partial: d = tid>>2, seg = tid&3
    for (int jt = 0; jt < 16; jt++) {
        const int j0 = jt * 64;
        *(short8v*)&Ks[r0][cc8]      = *(const short8v*)(kb + (b * 1024 + j0 + r0) * 512 + h * 64 + cc8);
        *(short8v*)&Ks[r0 + 32][cc8] = *(const short8v*)(kb + (b * 1024 + j0 + r0 + 32) * 512 + h * 64 + cc8);
        *(short8v*)&Vs[r0][cc8]      = *(const short8v*)(vT + ((size_t)z << 16) + (r0 << 10) + j0 + cc8);
        *(short8v*)&Vs[r0 + 32][cc8] = *(const short8v*)(vT + ((size_t)z << 16) + ((r0 + 32) << 10) + j0 + cc8);
        if (tid < 64) idxj[tid] = idx[b * 1024 + j0 + tid];
        __syncthreads();
        // colsum partial from Vs
        {
            const int d = tid >> 2, sg = (tid & 3) * 16;
            for (int u = 0; u < 16; u++) csum += bf2f(Vs[d][sg + u]);
        }
        // s = q k^T  (16 x 64)
        f32x4 as = {};
        for (int k0 = 0; k0 < 64; k0 += 32) {
            short8v a0 = *(short8v*)&Qs[lr][k0 + quad * 8];
            short8v b0 = *(short8v*)&Ks[wave * 16 + lr][k0 + quad * 8];
            as = __builtin_amdgcn_mfma_f32_16x16x32_bf16(a0, b0, as, 0, 0, 0);
        }
        for (int r = 0; r < 4; r++)
            Ss[quad * 4 + r][wave * 16 + lr] = as[r] * 0.125f;
        __syncthreads();
        // epilogue: mask, exp -> Sm (bf16), Es
        {
            const int ci = idxi[rL];
            f32x4 s4 = *(f32x4*)&Ss[rL][cL];
            short4v m4b, e4;
            for (int kk = 0; kk < 4; kk++) {
                const bool in = (idxj[cL + kk] == ci);
                const float sv = s4[kk];
                m4b[kk] = f2bf(in ? sv : 0.f);
                const float ev = (in && sv != 0.f) ? __expf(sv) : 0.f;
                rsum += ev;
                e4[kk] = f2bf(ev);
            }
            *(short4v*)&Sm[rL][j0 + cL] = m4b;
            *(short4v*)&Es[rL][cL] = e4;
        }
        __syncthreads();
        // o += e @ v  (16 x 64)
        for (int k0 = 0; k0 < 64; k0 += 32) {
            short8v a0 = *(short8v*)&Es[lr][k0 + quad * 8];
            short8v b0 = *(short8v*)&Vs[wave * 16 + lr][k0 + quad * 8];
            acc_o = __builtin_amdgcn_mfma_f32_16x16x32_bf16(a0, b0, acc_o, 0, 0, 0);
        }
        __syncthreads();
    }
    // reductions
    rowpart[rL][cI] = rsum;
    cpart[tid >> 2][tid & 3] = csum;
    __syncthreads();
    if (tid < 16) {
        float v = 0.f;
        for (int s = 0; s < 16; s++) v += rowpart[tid][s];
        invL[tid] = 1.f / (v + 1e-6f);
    } else if (tid >= 64 && tid < 128) {
        const int d = tid - 64;
        csL[d] = cpart[d][0] + cpart[d][1] + cpart[d][2] + cpart[d][3];
    }
    __syncthreads();
    // o epilogue: normalize + eps*colsum, store bf16
    {
        const float epsN = 1e-6f / 1024.f;
        for (int r = 0; r < 4; r++) {
            int iLoc = quad * 4 + r;
            int d = wave * 16 + lr;
            float val = (acc_o[r] + epsN * csL[d]) * invL[iLoc];
            oh[((size_t)(b * 1024 + i0 + iLoc)) * 512 + h * 64 + d] = f2bf(val);
        }
    }
    // WRITE PHASE: full contiguous 4 KB rows, plain stores, no barriers
    const int tc = tid * 4;
    const f32x4 zv = {0.f, 0.f, 0.f, 0.f};
    for (int r = 0; r < 16; r++) {
        const int ci = idxi[r];
        short4v sm4 = *(short4v*)&Sm[r][tc];
        f32x4 mv;
        mv[0] = bf2f(sm4[0]); mv[1] = bf2f(sm4[1]);
        mv[2] = bf2f(sm4[2]); mv[3] = bf2f(sm4[3]);
        float* basebh = attn + (((size_t)(b * 64 + h)) << 20) + (((size_t)(i0 + r)) << 10) + tc;
        for (int c = 0; c < 8; c++) {
            f32x4 w = (c == ci) ? mv : zv;
            *(f32x4*)(basebh + ((size_t)c << 23)) = w;
        }
    }
}

// ---------------------------------------------------------------- proj GEMM + bias (inline Wp cast)
__global__ __launch_bounds__(256) void proj_kernel(
    const short* __restrict__ oh, const float* __restrict__ wp,
    const float* __restrict__ bias, float* __restrict__ out) {
    __shared__ short As[64][40];
    __shared__ short Bs[64][40];
    const int tid = threadIdx.x;
    const int m0 = blockIdx.y * 64, n0 = blockIdx.x * 64;
    const int lane = tid & 63, wave = tid >> 6;
    const int wm = wave >> 1, wn = wave & 1, quad = lane >> 4, lr = lane & 15;
    const int row = tid >> 2, c0 = (tid & 3) * 8;
    f32x4 acc[2][2] = {};
    for (int kt = 0; kt < 512; kt += 32) {
        *(short8v*)&As[row][c0] = *(const short8v*)(oh + (m0 + row) * 512 + kt + c0);
        *(short8v*)&Bs[row][c0] = cvt8(wp + (n0 + row) * 512 + kt + c0);
        __syncthreads();
        short8v a0 = *(short8v*)&As[wm * 32 + lr][quad * 8];
        short8v a1 = *(short8v*)&As[wm * 32 + 16 + lr][quad * 8];
        short8v b0 = *(short8v*)&Bs[wn * 32 + lr][quad * 8];
        short8v b1 = *(short8v*)&Bs[wn * 32 + 16 + lr][quad * 8];
        acc[0][0] = __builtin_amdgcn_mfma_f32_16x16x32_bf16(a0, b0, acc[0][0], 0, 0, 0);
        acc[0][1] = __builtin_amdgcn_mfma_f32_16x16x32_bf16(a0, b1, acc[0][1], 0, 0, 0);
        acc[1][0] = __builtin_amdgcn_mfma_f32_16x16x32_bf16(a1, b0, acc[1][0], 0, 0, 0);
        acc[1][1] = __builtin_amdgcn_mfma_f32_16x16x32_bf16(a1, b1, acc[1][1], 0, 0, 0);
        __syncthreads();
    }
    for (int sm = 0; sm < 2; sm++)
        for (int sn = 0; sn < 2; sn++)
            for (int r = 0; r < 4; r++) {
                int m = m0 + wm * 32 + sm * 16 + quad * 4 + r;
                int n = n0 + wn * 32 + sn * 16 + lr;
                out[(size_t)m * 512 + n] = acc[sm][sn][r] + bias[n];
            }
}

// ---------------------------------------------------------------- launch
extern "C" void kernel_launch(void* const* d_in, const int* in_sizes, int n_in,
                              void* d_out, int out_size, void* d_ws, size_t ws_size,
                              hipStream_t stream) {
    const float* x     = (const float*)d_in[0];
    const int*   idx   = (const int*)d_in[2];
    const float* Wq    = (const float*)d_in[4];
    const float* Wk    = (const float*)d_in[5];
    const float* Wv    = (const float*)d_in[6];
    const float* Wp    = (const float*)d_in[7];
    const float* bproj = (const float*)d_in[8];

    float* out  = (float*)d_out;
    float* attn = out + (size_t)NB * NN * NC;   // attn_map region (B,K,H,N,N)

    char* ws = (char*)d_ws;
    short* qb = (short*)(ws + 0);          // 2 MB
    short* kb = (short*)(ws + 2097152);    // 2 MB
    short* vT = (short*)(ws + 4194304);    // 2 MB
    short* oh = (short*)(ws + 6291456);    // 2 MB

    qkv_kernel<<<dim3(8, 32, 3), 256, 0, stream>>>(x, Wq, Wk, Wv, qb, kb, vT);
    attn_fused_kernel<<<dim3(64, 16), 256, 0, stream>>>(qb, kb, vT, idx, attn, oh);
    proj_kernel<<<dim3(8, 32, 1), 256, 0, stream>>>(oh, Wp, bproj, out);
}

// Round 8
// 601.756 us; speedup vs baseline: 1.0282x; 1.0282x over previous
//
#include <hip/hip_runtime.h>
#include <hip/hip_bf16.h>
#include <cstdint>
#include <cstddef>

// Problem constants (B=2, N=1024, C=512, H=8, hd=64, clusters=8)
#define NB   2
#define NN   1024
#define NC   512
#define NH   8
#define NHD  64
#define NK   8

typedef __attribute__((ext_vector_type(8))) short short8v;   // 8 bf16 (4 VGPRs)
typedef __attribute__((ext_vector_type(4))) short short4v;
typedef __attribute__((ext_vector_type(4))) float f32x4;

__device__ __forceinline__ short f2bf(float f) {
    union { float f; unsigned u; } v; v.f = f;
    unsigned r = v.u + 0x7FFFu + ((v.u >> 16) & 1u);   // RNE
    return (short)(r >> 16);
}
__device__ __forceinline__ float bf2f(short s) {
    union { unsigned u; float f; } v;
    v.u = ((unsigned)(unsigned short)s) << 16;
    return v.f;
}
__device__ __forceinline__ short8v cvt8(const float* p) {
    float4 a = *(const float4*)p;
    float4 b = *(const float4*)(p + 4);
    short8v r;
    r[0] = f2bf(a.x); r[1] = f2bf(a.y); r[2] = f2bf(a.z); r[3] = f2bf(a.w);
    r[4] = f2bf(b.x); r[5] = f2bf(b.y); r[6] = f2bf(b.z); r[7] = f2bf(b.w);
    return r;
}

// ---------------------------------------------------------------- QKV GEMM (inline f32->bf16 cast)
// q/k: (2048,512) bf16.  v stored transposed per head: vT[b,h,d,i] bf16.
__global__ __launch_bounds__(256) void qkv_kernel(
    const float* __restrict__ x, const float* __restrict__ wq,
    const float* __restrict__ wk, const float* __restrict__ wv,
    short* __restrict__ qb, short* __restrict__ kb, short* __restrict__ vT) {
    __shared__ short As[64][40];
    __shared__ short Bs[64][40];
    const int tid = threadIdx.x;
    const int z = blockIdx.z;
    const float* Bsrc = (z == 0) ? wq : ((z == 1) ? wk : wv);
    const int m0 = blockIdx.y * 64, n0 = blockIdx.x * 64;
    const int lane = tid & 63, wave = tid >> 6;
    const int wm = wave >> 1, wn = wave & 1, quad = lane >> 4, lr = lane & 15;
    const int row = tid >> 2, c0 = (tid & 3) * 8;
    f32x4 acc[2][2] = {};
    for (int kt = 0; kt < 512; kt += 32) {
        *(short8v*)&As[row][c0] = cvt8(x + (m0 + row) * 512 + kt + c0);
        *(short8v*)&Bs[row][c0] = cvt8(Bsrc + (n0 + row) * 512 + kt + c0);
        __syncthreads();
        short8v a0 = *(short8v*)&As[wm * 32 + lr][quad * 8];
        short8v a1 = *(short8v*)&As[wm * 32 + 16 + lr][quad * 8];
        short8v b0 = *(short8v*)&Bs[wn * 32 + lr][quad * 8];
        short8v b1 = *(short8v*)&Bs[wn * 32 + 16 + lr][quad * 8];
        acc[0][0] = __builtin_amdgcn_mfma_f32_16x16x32_bf16(a0, b0, acc[0][0], 0, 0, 0);
        acc[0][1] = __builtin_amdgcn_mfma_f32_16x16x32_bf16(a0, b1, acc[0][1], 0, 0, 0);
        acc[1][0] = __builtin_amdgcn_mfma_f32_16x16x32_bf16(a1, b0, acc[1][0], 0, 0, 0);
        acc[1][1] = __builtin_amdgcn_mfma_f32_16x16x32_bf16(a1, b1, acc[1][1], 0, 0, 0);
        __syncthreads();
    }
    for (int sm = 0; sm < 2; sm++)
        for (int sn = 0; sn < 2; sn++)
            for (int r = 0; r < 4; r++) {
                int m = m0 + wm * 32 + sm * 16 + quad * 4 + r;
                int n = n0 + wn * 32 + sn * 16 + lr;
                short v = f2bf(acc[sm][sn][r]);
                if (z == 0) qb[m * 512 + n] = v;
                else if (z == 1) kb[m * 512 + n] = v;
                else {
                    int bb = m >> 10, i = m & 1023, h = n >> 6, d = n & 63;
                    vT[(size_t)(((bb * 8 + h) * 64 + d) << 10) + i] = v;
                }
            }
}

// ---------------------------------------------------------------- colsum of v per (b,h)
__global__ __launch_bounds__(256) void colsum_kernel(
    const short* __restrict__ vT, float* __restrict__ colsum) {
    __shared__ float cp[8][33];
    const int blk = blockIdx.x;     // bh*8 + dgroup
    const int bh = blk >> 3, dg = blk & 7;
    const int t = threadIdx.x;
    const int dl = t >> 5, seg = t & 31;
    const short* p = vT + (((size_t)(bh * 64 + dg * 8 + dl)) << 10) + seg * 32;
    float s = 0.f;
    for (int k = 0; k < 32; k += 8) {
        short8v v = *(const short8v*)(p + k);
        for (int j = 0; j < 8; j++) s += bf2f(v[j]);
    }
    cp[dl][seg] = s;
    __syncthreads();
    if (t < 8) {
        float v = 0.f;
        for (int s2 = 0; s2 < 32; s2++) v += cp[t][s2];
        colsum[bh * 64 + dg * 8 + t] = v;
    }
}

// ---------------------------------------------------------------- fused attention, spatially specialized
// Grid 5120 blocks, interleaved 4:1 zero:value so the 470 MB zero stream and
// the compute run CONCURRENTLY across every CU from t=0.
//  - zero blocks (4096): stream zeros over rows where idx[b,i]!=c (fill shape)
//  - value blocks (1024): 16-row strip; per j-tile: s-MFMA -> in-register
//    mask/exp on C-layout regs -> direct f32 stores of the ci-slice rows
//    (4 rows x 64 B full lines per instruction) + e -> Es (A-layout, scalar
//    ds_write) -> o-MFMA. Normalize + eps*colsum in o epilogue.
__global__ __launch_bounds__(256) void attn_fused_kernel(
    const short* __restrict__ qb, const short* __restrict__ kb,
    const short* __restrict__ vT, const int* __restrict__ idx,
    const float* __restrict__ colsum, float* __restrict__ attn,
    short* __restrict__ oh) {
    __shared__ short Qs[16][72], Ks[64][72], Vs[64][72], Es[16][72];
    __shared__ float rowpart[16][68];
    __shared__ float invL[16], csL[64];
    __shared__ int idxi[32], idxj[64];
    const int tid = threadIdx.x;
    const int bi = blockIdx.x;
    const int slot = bi % 5;

    if (slot != 4) {
        // ---------------- zero block: zb in 0..4095
        const int zb = (bi / 5) * 4 + slot;
        const int itile = zb & 31, bch = zb >> 5;        // bch = b*64 + c*8 + h
        const int c = (bch >> 3) & 7, b = bch >> 6;
        if (tid < 32) idxi[tid] = idx[b * 1024 + itile * 32 + tid];
        __syncthreads();
        float* base = attn + ((size_t)bch << 20) + ((size_t)itile << 15);
        const f32x4 zv = {0.f, 0.f, 0.f, 0.f};
        for (int rr = 0; rr < 32; rr++) {
            if (idxi[rr] == c) continue;
            *(f32x4*)(base + (rr << 10) + tid * 4) = zv;
        }
        return;
    }

    // ---------------- value block: vb in 0..1023
    const int vb = bi / 5;
    const int z = vb >> 6, b = z >> 3, h = z & 7;
    const int i0 = (vb & 63) * 16;
    const int lane = tid & 63, wave = tid >> 6;
    const int quad = lane >> 4, lr = lane & 15;
    const int r0 = tid >> 3, cc8 = (tid & 7) * 8;       // staging rows 0..31
    {
        int rq = tid >> 4, cq = (tid & 15) * 4;
        *(short4v*)&Qs[rq][cq] = *(const short4v*)(qb + (b * 1024 + i0 + rq) * 512 + h * 64 + cq);
    }
    if (tid < 16) idxi[tid] = idx[b * 1024 + i0 + tid];
    else if (tid >= 64 && tid < 128) csL[tid - 64] = colsum[z * 64 + (tid - 64)];
    f32x4 acc_o = {};
    float rsum[4] = {0.f, 0.f, 0.f, 0.f};               // rows quad*4+r (fixed per thread)
    for (int jt = 0; jt < 16; jt++) {
        const int j0 = jt * 64;
        *(short8v*)&Ks[r0][cc8]      = *(const short8v*)(kb + (b * 1024 + j0 + r0) * 512 + h * 64 + cc8);
        *(short8v*)&Ks[r0 + 32][cc8] = *(const short8v*)(kb + (b * 1024 + j0 + r0 + 32) * 512 + h * 64 + cc8);
        *(short8v*)&Vs[r0][cc8]      = *(const short8v*)(vT + ((size_t)z << 16) + (r0 << 10) + j0 + cc8);
        *(short8v*)&Vs[r0 + 32][cc8] = *(const short8v*)(vT + ((size_t)z << 16) + ((r0 + 32) << 10) + j0 + cc8);
        if (tid < 64) idxj[tid] = idx[b * 1024 + j0 + tid];
        __syncthreads();
        // s = q k^T (16x64): wave covers cols wave*16..+15
        f32x4 as = {};
        for (int k0 = 0; k0 < 64; k0 += 32) {
            short8v a0 = *(short8v*)&Qs[lr][k0 + quad * 8];
            short8v b0 = *(short8v*)&Ks[wave * 16 + lr][k0 + quad * 8];
            as = __builtin_amdgcn_mfma_f32_16x16x32_bf16(a0, b0, as, 0, 0, 0);
        }
        // in-register epilogue on C-layout: lane holds col wave*16+lr, rows quad*4+r
        const int colc = idxj[wave * 16 + lr];
        for (int r = 0; r < 4; r++) {
            const int row = quad * 4 + r;
            const int ci = idxi[row];
            const float sv = as[r] * 0.125f;
            const bool in = (colc == ci);
            const float w = in ? sv : 0.f;
            const float ev = (in && sv != 0.f) ? __expf(sv) : 0.f;
            rsum[r] += ev;
            Es[row][wave * 16 + lr] = f2bf(ev);
            attn[(((size_t)(b * 64 + ci * 8 + h)) << 20) + (((size_t)(i0 + row)) << 10) + j0 + wave * 16 + lr] = w;
        }
        __syncthreads();
        // o += e @ v (16x64): wave covers d cols wave*16..+15
        for (int k0 = 0; k0 < 64; k0 += 32) {
            short8v a0 = *(short8v*)&Es[lr][k0 + quad * 8];
            short8v b0 = *(short8v*)&Vs[wave * 16 + lr][k0 + quad * 8];
            acc_o = __builtin_amdgcn_mfma_f32_16x16x32_bf16(a0, b0, acc_o, 0, 0, 0);
        }
        __syncthreads();
    }
    // row-sum reduction
    for (int r = 0; r < 4; r++) rowpart[quad * 4 + r][wave * 16 + lr] = rsum[r];
    __syncthreads();
    if (tid < 16) {
        float v = 0.f;
        for (int s = 0; s < 64; s++) v += rowpart[tid][s];
        invL[tid] = 1.f / (v + 1e-6f);
    }
    __syncthreads();
    // o epilogue
    const float epsN = 1e-6f / 1024.f;
    for (int r = 0; r < 4; r++) {
        const int row = quad * 4 + r;
        const int d = wave * 16 + lr;
        float val = (acc_o[r] + epsN * csL[d]) * invL[row];
        oh[((size_t)(b * 1024 + i0 + row)) * 512 + h * 64 + d] = f2bf(val);
    }
}

// ---------------------------------------------------------------- proj GEMM + bias (inline Wp cast)
__global__ __launch_bounds__(256) void proj_kernel(
    const short* __restrict__ oh, const float* __restrict__ wp,
    const float* __restrict__ bias, float* __restrict__ out) {
    __shared__ short As[64][40];
    __shared__ short Bs[64][40];
    const int tid = threadIdx.x;
    const int m0 = blockIdx.y * 64, n0 = blockIdx.x * 64;
    const int lane = tid & 63, wave = tid >> 6;
    const int wm = wave >> 1, wn = wave & 1, quad = lane >> 4, lr = lane & 15;
    const int row = tid >> 2, c0 = (tid & 3) * 8;
    f32x4 acc[2][2] = {};
    for (int kt = 0; kt < 512; kt += 32) {
        *(short8v*)&As[row][c0] = *(const short8v*)(oh + (m0 + row) * 512 + kt + c0);
        *(short8v*)&Bs[row][c0] = cvt8(wp + (n0 + row) * 512 + kt + c0);
        __syncthreads();
        short8v a0 = *(short8v*)&As[wm * 32 + lr][quad * 8];
        short8v a1 = *(short8v*)&As[wm * 32 + 16 + lr][quad * 8];
        short8v b0 = *(short8v*)&Bs[wn * 32 + lr][quad * 8];
        short8v b1 = *(short8v*)&Bs[wn * 32 + 16 + lr][quad * 8];
        acc[0][0] = __builtin_amdgcn_mfma_f32_16x16x32_bf16(a0, b0, acc[0][0], 0, 0, 0);
        acc[0][1] = __builtin_amdgcn_mfma_f32_16x16x32_bf16(a0, b1, acc[0][1], 0, 0, 0);
        acc[1][0] = __builtin_amdgcn_mfma_f32_16x16x32_bf16(a1, b0, acc[1][0], 0, 0, 0);
        acc[1][1] = __builtin_amdgcn_mfma_f32_16x16x32_bf16(a1, b1, acc[1][1], 0, 0, 0);
        __syncthreads();
    }
    for (int sm = 0; sm < 2; sm++)
        for (int sn = 0; sn < 2; sn++)
            for (int r = 0; r < 4; r++) {
                int m = m0 + wm * 32 + sm * 16 + quad * 4 + r;
                int n = n0 + wn * 32 + sn * 16 + lr;
                out[(size_t)m * 512 + n] = acc[sm][sn][r] + bias[n];
            }
}

// ---------------------------------------------------------------- launch
extern "C" void kernel_launch(void* const* d_in, const int* in_sizes, int n_in,
                              void* d_out, int out_size, void* d_ws, size_t ws_size,
                              hipStream_t stream) {
    const float* x     = (const float*)d_in[0];
    const int*   idx   = (const int*)d_in[2];
    const float* Wq    = (const float*)d_in[4];
    const float* Wk    = (const float*)d_in[5];
    const float* Wv    = (const float*)d_in[6];
    const float* Wp    = (const float*)d_in[7];
    const float* bproj = (const float*)d_in[8];

    float* out  = (float*)d_out;
    float* attn = out + (size_t)NB * NN * NC;   // attn_map region (B,K,H,N,N)

    char* ws = (char*)d_ws;
    short* qb = (short*)(ws + 0);          // 2 MB
    short* kb = (short*)(ws + 2097152);    // 2 MB
    short* vT = (short*)(ws + 4194304);    // 2 MB
    short* oh = (short*)(ws + 6291456);    // 2 MB
    float* colsum = (float*)(ws + 8388608);// 4 KB

    qkv_kernel<<<dim3(8, 32, 3), 256, 0, stream>>>(x, Wq, Wk, Wv, qb, kb, vT);
    colsum_kernel<<<128, 256, 0, stream>>>(vT, colsum);
    attn_fused_kernel<<<5120, 256, 0, stream>>>(qb, kb, vT, idx, colsum, attn, oh);
    proj_kernel<<<dim3(8, 32, 1), 256, 0, stream>>>(oh, Wp, bproj, out);
}